// Round 10
// baseline (220.822 us; speedup 1.0000x reference)
//
#include <hip/hip_runtime.h>

// Problem constants (match reference setup_inputs)
#define GH 720
#define GW 1280
#define GT 20
#define GB 8
#define NEV 500000
#define TOTAL (GB * NEV)

// Coarse partition: row-band of 8 rows per batch -> (b, y>>3)
#define CY 90                     // GH/8
#define NCOARSE (GB * CY)         // 720
#define CAPC 6144                 // slots/coarse bucket (avg ~5555, max ~5930)
#define PAD 32                    // u32 stride per counter -> one 128B line each
#define EVB 8192                  // events per k_part block
#define NBLK1 ((TOTAL + EVB - 1) / EVB)   // 489

// Accumulate tile: 20 t x 8 rows x 64 cols = 40 KB LDS
#define TY 8
#define TX 64
#define NTXB (GW / TX)            // 20
#define OVF_CAP (1u << 20)

typedef float vfloat4 __attribute__((ext_vector_type(4)));

// compact record (u32): x[0:10] | (y&7)[11:13] | p[14] | k0[15:19] | w1q[20:31] (12-bit)
// overflow record (uint2): word0 = x | y<<11 | p<<21 | k0<<22 | b<<27 ; word1 = w1 bits

// ---------------- Phase 0: zero padded coarse counters + overflow counter ----
__global__ __launch_bounds__(256) void k_zero(unsigned* __restrict__ gcnt)
{
    int i = blockIdx.x * blockDim.x + threadIdx.x;
    if (i < NCOARSE * PAD + 1) gcnt[i] = 0u;   // gcnt[NCOARSE*PAD] = ovf counter
}

// ---------------- Phase 1: coarse partition, block-aggregated reservations ----
__global__ __launch_bounds__(256) void k_part(
    const float4* __restrict__ ev, const int* __restrict__ counts,
    unsigned* __restrict__ gcnt, unsigned* __restrict__ buckets,
    uint2* __restrict__ ovf)
{
    __shared__ unsigned hist[NCOARSE];
    __shared__ unsigned lbase[NCOARSE];
    __shared__ unsigned hist2[NCOARSE];
    const int tid = threadIdx.x;
    const int base = blockIdx.x * EVB + tid;

    for (int c = tid; c < NCOARSE; c += 256) { hist[c] = 0u; hist2[c] = 0u; }
    __syncthreads();

    // pass 1: per-block histogram (LDS atomics only)
    for (int j = 0; j < EVB / 256; j++) {
        int i = base + j * 256;
        if (i >= TOTAL) break;
        int b = i / NEV;                    // constant divisor -> magic-mul
        int n = i - b * NEV;
        if (n >= counts[b]) continue;
        float4 e = ev[i];
        int y = min(max((int)e.y, 0), GH - 1);
        atomicAdd(&hist[b * CY + (y >> 3)], 1u);
    }
    __syncthreads();

    // reserve one contiguous range per (block, bucket): ~720 global atomics/block
    for (int c = tid; c < NCOARSE; c += 256) {
        unsigned h = hist[c];
        lbase[c] = h ? atomicAdd(&gcnt[c * PAD], h) : 0u;
    }
    __syncthreads();

    // pass 2: rank in LDS, write compact record to reserved slot
    for (int j = 0; j < EVB / 256; j++) {
        int i = base + j * 256;
        if (i >= TOTAL) break;
        int b = i / NEV;
        int n = i - b * NEV;
        if (n >= counts[b]) continue;
        float4 e = ev[i];
        int x = min(max((int)e.x, 0), GW - 1);
        int y = min(max((int)e.y, 0), GH - 1);
        int c = b * CY + (y >> 3);

        float tb = e.z * (float)(GT - 1);
        int k0 = (int)floorf(tb);
        float w1 = tb - (float)k0;          // before clamping, matches reference
        int k0c = min(max(k0, 0), GT - 1);
        unsigned p = (e.w > 0.5f) ? 1u : 0u;

        unsigned pos = lbase[c] + atomicAdd(&hist2[c], 1u);
        if (pos < CAPC) {
            unsigned w1q = __float2uint_rn(w1 * 4095.0f);
            unsigned rec = (unsigned)x | ((unsigned)(y & 7) << 11) | (p << 14)
                         | ((unsigned)k0c << 15) | (w1q << 20);
            buckets[(size_t)c * CAPC + pos] = rec;
        } else {
            unsigned word0 = (unsigned)x | ((unsigned)y << 11) | (p << 21)
                           | ((unsigned)k0c << 22) | ((unsigned)b << 27);
            unsigned o = atomicAdd(&gcnt[NCOARSE * PAD], 1u);
            if (o < OVF_CAP) ovf[o] = make_uint2(word0, __float_as_uint(w1));
        }
    }
}

// ---------------- Phase 2: fused per-coarse-bin accumulate + NT write --------
__global__ __launch_bounds__(256) void k_faccum(
    const unsigned* __restrict__ buckets, const unsigned* __restrict__ gcnt,
    float* __restrict__ out)
{
    __shared__ unsigned stash[CAPC];       // 24.6 KB
    __shared__ float tile[GT * TY * TX];   // 40 KB
    const int c = blockIdx.x;
    const int tid = threadIdx.x;

    unsigned m = min(gcnt[c * PAD], (unsigned)CAPC);
    // one coalesced burst: bucket is already bin-contiguous (global reservations)
    for (unsigned i = tid; i < m; i += 256)
        stash[i] = buckets[(size_t)c * CAPC + i];
    __syncthreads();

    const int b  = c / CY;
    const int y0 = (c % CY) * TY;
    vfloat4* t4 = (vfloat4*)tile;
    vfloat4* o4 = (vfloat4*)out;

    for (int tx = 0; tx < NTXB; tx++) {
        for (int j = tid; j < GT * TY * (TX / 4); j += 256)
            t4[j] = (vfloat4){0.f, 0.f, 0.f, 0.f};
        __syncthreads();

        for (unsigned idx = tid; idx < m; idx += 256) {
            unsigned r = stash[idx];
            if ((int)((r & 2047u) >> 6) != tx) continue;
            int xx = r & 63;
            int yy = (r >> 11) & 7;
            float pol = ((r >> 14) & 1u) ? 1.0f : -1.0f;
            int k0 = (r >> 15) & 31;
            float w1 = (float)(r >> 20) * (1.0f / 4095.0f);
            int k1 = min(k0 + 1, GT - 1);
            atomicAdd(&tile[(k0 * TY + yy) * TX + xx], pol * (1.0f - w1));
            atomicAdd(&tile[(k1 * TY + yy) * TX + xx], pol * w1);
        }
        __syncthreads();

        // 2560 float4 per tile; 16 float4 per (k,yy) row of 64 floats
        for (int j = tid; j < GT * TY * (TX / 4); j += 256) {
            int row = j >> 4;              // k*TY + yy
            int col = j & 15;
            int k  = row >> 3;
            int yy = row & 7;
            int off = ((b * GT + k) * GH + (y0 + yy)) * (GW / 4) + tx * (TX / 4) + col;
            __builtin_nontemporal_store(t4[j], &o4[off]);
        }
        __syncthreads();
    }
}

// ---------------- Phase 3: replay overflow events (normally zero) -------------
__global__ __launch_bounds__(256) void k_overflow(
    const uint2* __restrict__ ovf, const unsigned* __restrict__ gcnt,
    float* __restrict__ out)
{
    unsigned n = min(gcnt[NCOARSE * PAD], OVF_CAP);
    for (unsigned i = blockIdx.x * blockDim.x + threadIdx.x; i < n;
         i += gridDim.x * blockDim.x) {
        uint2 r = ovf[i];
        int x  = r.x & 2047;
        int y  = (r.x >> 11) & 1023;
        int p  = (r.x >> 21) & 1;
        int k0 = (r.x >> 22) & 31;
        int b  = (r.x >> 27) & 7;
        float w1 = __uint_as_float(r.y);
        float w0 = 1.0f - w1;
        float pol = p ? 1.0f : -1.0f;
        int k1 = min(k0 + 1, GT - 1);
        atomicAdd(&out[((b * GT + k0) * GH + y) * GW + x], pol * w0);
        atomicAdd(&out[((b * GT + k1) * GH + y) * GW + x], pol * w1);
    }
}

// ---------------- Fallback (round-1 path) ----------------
__global__ __launch_bounds__(256) void ev2voxel_scatter(
    const float4* __restrict__ ev, const int* __restrict__ counts,
    float* __restrict__ out)
{
    int i = blockIdx.x * blockDim.x + threadIdx.x;
    if (i >= TOTAL) return;
    int b = i / NEV;
    int n = i - b * NEV;
    if (n >= counts[b]) return;
    float4 e = ev[i];
    int x = min(max((int)e.x, 0), GW - 1);
    int y = min(max((int)e.y, 0), GH - 1);
    float pol = e.w * 2.0f - 1.0f;
    float tb = e.z * (float)(GT - 1);
    int k0 = (int)floorf(tb);
    float w1 = tb - (float)k0;
    float w0 = 1.0f - w1;
    int k0c = min(max(k0, 0), GT - 1);
    int k1c = min(max(k0 + 1, 0), GT - 1);
    int rowbase = (b * GT) * GH;
    atomicAdd(&out[(rowbase + k0c * GH + y) * GW + x], pol * w0);
    atomicAdd(&out[(rowbase + k1c * GH + y) * GW + x], pol * w1);
}

extern "C" void kernel_launch(void* const* d_in, const int* in_sizes, int n_in,
                              void* d_out, int out_size, void* d_ws, size_t ws_size,
                              hipStream_t stream) {
    const float4* ev = (const float4*)d_in[0];   // (B, N, 4) fp32
    const int* counts = (const int*)d_in[1];     // (B,) int
    float* out = (float*)d_out;                  // (B, T, H, W) fp32

    // workspace (u32 units): gcnt[NCOARSE*PAD + PAD], buckets[NCOARSE*CAPC] u32,
    // (8B align) ovf[OVF_CAP] uint2
    const size_t gcnt_off   = 0;
    const size_t bucket_off = (size_t)NCOARSE * PAD + PAD;
    size_t ovf_off          = bucket_off + (size_t)NCOARSE * CAPC;
    if (ovf_off & 1) ovf_off++;
    const size_t need_bytes = (ovf_off + (size_t)OVF_CAP * 2) * 4;

    if (ws_size < need_bytes) {
        (void)hipMemsetAsync(out, 0, (size_t)out_size * sizeof(float), stream);
        ev2voxel_scatter<<<(TOTAL + 255) / 256, 256, 0, stream>>>(ev, counts, out);
        return;
    }

    unsigned* ws = (unsigned*)d_ws;
    unsigned* gcnt    = ws + gcnt_off;
    unsigned* buckets = ws + bucket_off;
    uint2*    ovf     = (uint2*)(ws + ovf_off);

    k_zero<<<(NCOARSE * PAD + 1 + 255) / 256, 256, 0, stream>>>(gcnt);
    k_part<<<NBLK1, 256, 0, stream>>>(ev, counts, gcnt, buckets, ovf);
    k_faccum<<<NCOARSE, 256, 0, stream>>>(buckets, gcnt, out);
    k_overflow<<<64, 256, 0, stream>>>(ovf, gcnt, out);
}

// Round 11
// 191.870 us; speedup vs baseline: 1.1509x; 1.1509x over previous
//
#include <hip/hip_runtime.h>

// Problem constants (match reference setup_inputs)
#define GH 720
#define GW 1280
#define GT 20
#define GB 8
#define NEV 500000
#define TOTAL (GB * NEV)

// Coarse partition: row-band of 8 rows per batch -> (b, y>>3)
#define CY 90                     // GH/8
#define NCOARSE (GB * CY)         // 720
#define CAPC 6144                 // slots/coarse bucket (avg ~4167, hard max ~5930)
#define PAD 32                    // u32 stride per counter -> one 128B line each
#define EVB 8192                  // events per k_part block
#define NBLK1 ((TOTAL + EVB - 1) / EVB)   // 489

// Accumulate tile: 20 t x 8 rows x 64 cols = 40 KB LDS
#define TY 8
#define TX 64
#define NTXB (GW / TX)            // 20
#define OVF_CAP (1u << 20)

typedef float vfloat4 __attribute__((ext_vector_type(4)));

// compact record (u32): x[0:10] | (y&7)[11:13] | p[14] | k0[15:19] | w1q[20:31] (12-bit)
// overflow record (uint2): word0 = x | y<<11 | p<<21 | k0<<22 | b<<27 ; word1 = w1 bits

// ---------------- Phase 0: zero padded coarse counters + overflow counter ----
__global__ __launch_bounds__(256) void k_zero(unsigned* __restrict__ gcnt)
{
    int i = blockIdx.x * blockDim.x + threadIdx.x;
    if (i < NCOARSE * PAD + 1) gcnt[i] = 0u;   // gcnt[NCOARSE*PAD] = ovf counter
}

// ---------------- Phase 1: coarse partition, block-aggregated reservations ----
__global__ __launch_bounds__(256) void k_part(
    const float4* __restrict__ ev, const int* __restrict__ counts,
    unsigned* __restrict__ gcnt, unsigned* __restrict__ buckets,
    uint2* __restrict__ ovf)
{
    __shared__ unsigned hist[NCOARSE];
    __shared__ unsigned lbase[NCOARSE];
    __shared__ unsigned hist2[NCOARSE];
    const int tid = threadIdx.x;
    const int base = blockIdx.x * EVB + tid;

    for (int c = tid; c < NCOARSE; c += 256) { hist[c] = 0u; hist2[c] = 0u; }
    __syncthreads();

    // pass 1: per-block histogram (LDS atomics only)
    for (int j = 0; j < EVB / 256; j++) {
        int i = base + j * 256;
        if (i >= TOTAL) break;
        int b = i / NEV;                    // constant divisor -> magic-mul
        int n = i - b * NEV;
        if (n >= counts[b]) continue;
        float4 e = ev[i];
        int y = min(max((int)e.y, 0), GH - 1);
        atomicAdd(&hist[b * CY + (y >> 3)], 1u);
    }
    __syncthreads();

    // reserve one contiguous range per (block, bucket): ~720 global atomics/block
    for (int c = tid; c < NCOARSE; c += 256) {
        unsigned h = hist[c];
        lbase[c] = h ? atomicAdd(&gcnt[c * PAD], h) : 0u;
    }
    __syncthreads();

    // pass 2: rank in LDS, write compact record to reserved slot
    for (int j = 0; j < EVB / 256; j++) {
        int i = base + j * 256;
        if (i >= TOTAL) break;
        int b = i / NEV;
        int n = i - b * NEV;
        if (n >= counts[b]) continue;
        float4 e = ev[i];
        int x = min(max((int)e.x, 0), GW - 1);
        int y = min(max((int)e.y, 0), GH - 1);
        int c = b * CY + (y >> 3);

        float tb = e.z * (float)(GT - 1);
        int k0 = (int)floorf(tb);
        float w1 = tb - (float)k0;          // before clamping, matches reference
        int k0c = min(max(k0, 0), GT - 1);
        unsigned p = (e.w > 0.5f) ? 1u : 0u;

        unsigned pos = lbase[c] + atomicAdd(&hist2[c], 1u);
        if (pos < CAPC) {
            unsigned w1q = __float2uint_rn(w1 * 4095.0f);
            unsigned rec = (unsigned)x | ((unsigned)(y & 7) << 11) | (p << 14)
                         | ((unsigned)k0c << 15) | (w1q << 20);
            buckets[(size_t)c * CAPC + pos] = rec;
        } else {
            unsigned word0 = (unsigned)x | ((unsigned)y << 11) | (p << 21)
                           | ((unsigned)k0c << 22) | ((unsigned)b << 27);
            unsigned o = atomicAdd(&gcnt[NCOARSE * PAD], 1u);
            if (o < OVF_CAP) ovf[o] = make_uint2(word0, __float_as_uint(w1));
        }
    }
}

// ---------------- Phase 2: fused accumulate: in-LDS tx-sort, then per-tile ---
__global__ __launch_bounds__(256) void k_faccum(
    const unsigned* __restrict__ buckets, const unsigned* __restrict__ gcnt,
    float* __restrict__ out)
{
    __shared__ unsigned stash[CAPC];       // 24.6 KB
    __shared__ float tile[GT * TY * TX];   // 40 KB (doubles as reorder scratch)
    __shared__ unsigned fhist[NTXB], foff[NTXB + 1], fh2[NTXB];
    const int c = blockIdx.x;
    const int tid = threadIdx.x;

    if (tid < NTXB) { fhist[tid] = 0u; fh2[tid] = 0u; }
    __syncthreads();

    unsigned m = min(gcnt[c * PAD], (unsigned)CAPC);
    // coalesced burst load + 20-bin x-tile histogram
    for (unsigned i = tid; i < m; i += 256) {
        unsigned r = buckets[(size_t)c * CAPC + i];
        stash[i] = r;
        atomicAdd(&fhist[(r & 2047u) >> 6], 1u);
    }
    __syncthreads();

    if (tid == 0) {
        unsigned s = 0;
        for (int t = 0; t < NTXB; t++) { foff[t] = s; s += fhist[t]; }
        foff[NTXB] = s;
    }
    __syncthreads();

    // rank-scatter into tile region (u32 scratch), then copy back: records
    // become x-tile-contiguous, so the tx loop touches each record once.
    unsigned* tmp = (unsigned*)tile;       // 10240 slots >= CAPC
    for (unsigned i = tid; i < m; i += 256) {
        unsigned r = stash[i];
        unsigned tx = (r & 2047u) >> 6;
        unsigned rk = atomicAdd(&fh2[tx], 1u);
        tmp[foff[tx] + rk] = r;
    }
    __syncthreads();
    for (unsigned i = tid; i < m; i += 256) stash[i] = tmp[i];
    __syncthreads();

    const int b  = c / CY;
    const int y0 = (c % CY) * TY;
    vfloat4* t4 = (vfloat4*)tile;
    vfloat4* o4 = (vfloat4*)out;

    for (int tx = 0; tx < NTXB; tx++) {
        for (int j = tid; j < GT * TY * (TX / 4); j += 256)
            t4[j] = (vfloat4){0.f, 0.f, 0.f, 0.f};
        __syncthreads();

        unsigned s1 = foff[tx + 1];
        for (unsigned idx = foff[tx] + tid; idx < s1; idx += 256) {
            unsigned r = stash[idx];
            int xx = r & 63;
            int yy = (r >> 11) & 7;
            float pol = ((r >> 14) & 1u) ? 1.0f : -1.0f;
            int k0 = (r >> 15) & 31;
            float w1 = (float)(r >> 20) * (1.0f / 4095.0f);
            int k1 = min(k0 + 1, GT - 1);
            atomicAdd(&tile[(k0 * TY + yy) * TX + xx], pol * (1.0f - w1));
            atomicAdd(&tile[(k1 * TY + yy) * TX + xx], pol * w1);
        }
        __syncthreads();

        // 2560 float4 per tile; 16 float4 per (k,yy) row of 64 floats
        for (int j = tid; j < GT * TY * (TX / 4); j += 256) {
            int row = j >> 4;              // k*TY + yy
            int col = j & 15;
            int k  = row >> 3;
            int yy = row & 7;
            int off = ((b * GT + k) * GH + (y0 + yy)) * (GW / 4) + tx * (TX / 4) + col;
            __builtin_nontemporal_store(t4[j], &o4[off]);
        }
        __syncthreads();
    }
}

// ---------------- Phase 3: replay overflow events (normally zero) -------------
__global__ __launch_bounds__(256) void k_overflow(
    const uint2* __restrict__ ovf, const unsigned* __restrict__ gcnt,
    float* __restrict__ out)
{
    unsigned n = min(gcnt[NCOARSE * PAD], OVF_CAP);
    for (unsigned i = blockIdx.x * blockDim.x + threadIdx.x; i < n;
         i += gridDim.x * blockDim.x) {
        uint2 r = ovf[i];
        int x  = r.x & 2047;
        int y  = (r.x >> 11) & 1023;
        int p  = (r.x >> 21) & 1;
        int k0 = (r.x >> 22) & 31;
        int b  = (r.x >> 27) & 7;
        float w1 = __uint_as_float(r.y);
        float w0 = 1.0f - w1;
        float pol = p ? 1.0f : -1.0f;
        int k1 = min(k0 + 1, GT - 1);
        atomicAdd(&out[((b * GT + k0) * GH + y) * GW + x], pol * w0);
        atomicAdd(&out[((b * GT + k1) * GH + y) * GW + x], pol * w1);
    }
}

// ---------------- Fallback (round-1 path) ----------------
__global__ __launch_bounds__(256) void ev2voxel_scatter(
    const float4* __restrict__ ev, const int* __restrict__ counts,
    float* __restrict__ out)
{
    int i = blockIdx.x * blockDim.x + threadIdx.x;
    if (i >= TOTAL) return;
    int b = i / NEV;
    int n = i - b * NEV;
    if (n >= counts[b]) return;
    float4 e = ev[i];
    int x = min(max((int)e.x, 0), GW - 1);
    int y = min(max((int)e.y, 0), GH - 1);
    float pol = e.w * 2.0f - 1.0f;
    float tb = e.z * (float)(GT - 1);
    int k0 = (int)floorf(tb);
    float w1 = tb - (float)k0;
    float w0 = 1.0f - w1;
    int k0c = min(max(k0, 0), GT - 1);
    int k1c = min(max(k0 + 1, 0), GT - 1);
    int rowbase = (b * GT) * GH;
    atomicAdd(&out[(rowbase + k0c * GH + y) * GW + x], pol * w0);
    atomicAdd(&out[(rowbase + k1c * GH + y) * GW + x], pol * w1);
}

extern "C" void kernel_launch(void* const* d_in, const int* in_sizes, int n_in,
                              void* d_out, int out_size, void* d_ws, size_t ws_size,
                              hipStream_t stream) {
    const float4* ev = (const float4*)d_in[0];   // (B, N, 4) fp32
    const int* counts = (const int*)d_in[1];     // (B,) int
    float* out = (float*)d_out;                  // (B, T, H, W) fp32

    // workspace (u32 units): gcnt[NCOARSE*PAD + PAD], buckets[NCOARSE*CAPC] u32,
    // (8B align) ovf[OVF_CAP] uint2
    const size_t gcnt_off   = 0;
    const size_t bucket_off = (size_t)NCOARSE * PAD + PAD;
    size_t ovf_off          = bucket_off + (size_t)NCOARSE * CAPC;
    if (ovf_off & 1) ovf_off++;
    const size_t need_bytes = (ovf_off + (size_t)OVF_CAP * 2) * 4;

    if (ws_size < need_bytes) {
        (void)hipMemsetAsync(out, 0, (size_t)out_size * sizeof(float), stream);
        ev2voxel_scatter<<<(TOTAL + 255) / 256, 256, 0, stream>>>(ev, counts, out);
        return;
    }

    unsigned* ws = (unsigned*)d_ws;
    unsigned* gcnt    = ws + gcnt_off;
    unsigned* buckets = ws + bucket_off;
    uint2*    ovf     = (uint2*)(ws + ovf_off);

    k_zero<<<(NCOARSE * PAD + 1 + 255) / 256, 256, 0, stream>>>(gcnt);
    k_part<<<NBLK1, 256, 0, stream>>>(ev, counts, gcnt, buckets, ovf);
    k_faccum<<<NCOARSE, 256, 0, stream>>>(buckets, gcnt, out);
    k_overflow<<<64, 256, 0, stream>>>(ovf, gcnt, out);
}